// Round 11
// baseline (580.052 us; speedup 1.0000x reference)
//
#include <hip/hip_runtime.h>
#include <cstdint>
#include <math.h>

// Problem constants: B=32, TXT_T=256, MEL_T=1600, N_MEL=40
#define BB   32
#define LLEN 256
#define TLEN 1600
#define NC   40
#define NEGPADF (-1.0e12f)
#define NEGPADD (-1.0e12)

#define LOG2E_F 1.4426950408889634f
#define LN2_F   0.6931471805599453f
#define C7F     1.4426950408889634e-7f  // 1e-7*log2e, folded into alpha lp
// log2(1+y) ~= y*(PA + y*(PB + y*PC)) on y in (0,1]; max err ~4e-3 [R16 pass]
#define PA_F 1.4426950f
#define PB_F (-0.6484000f)
#define PC_F 0.2057000f

#define NCHUNK (TLEN / 32)      // 50 chunks of 32 steps
#define NITER  (NCHUNK + 2)     // follower lags 2 chunks

// Output layout (floats): mdn_loss[32] | alignment[32*1600*256] | lp[32*256*1600]
#define OFF_ALIGN 32
#define OFF_LP    (32 + (size_t)BB * TLEN * LLEN)

// Workspace: Ad double[32*256*80] | Kcd double[32*256] | bufA2 (52.4MB) | path
#define WSB_A    0
#define WSB_KC   (WSB_A + (size_t)BB * LLEN * 80 * 8)
#define WSB_LPT  (WSB_KC + (size_t)BB * LLEN * 8)
#define WSB_PATH (WSB_LPT + (size_t)BB * TLEN * 64 * 16)

__device__ __forceinline__ int imin(int a, int b) { return a < b ? a : b; }

#define WAIT_LGKM0 0xC07F   // lgkmcnt(0) only                 [validated R2-R6]

// Barrier: compiler fence + raw s_barrier (vmcnt NOT drained -> data-ring
// global loads stay in flight; leader drains lgkm explicitly before this).
__device__ __forceinline__ void bar() {
  asm volatile("" ::: "memory");
  __builtin_amdgcn_s_barrier();
  asm volatile("" ::: "memory");
}

// DPP wave-rotate-right-1: lane i <- lane i-1, lane 0 <- lane 63. VALU-only.
__device__ __forceinline__ int rot1_i32(int x) {
  return __builtin_amdgcn_mov_dpp(x, 0x13C /*wave_ror:1*/, 0xF, 0xF, true);
}
__device__ __forceinline__ float rot1_f32(float x) {
  return __int_as_float(rot1_i32(__float_as_int(x)));
}
__device__ __forceinline__ double rot1_f64(double x) {
  long long v = __double_as_longlong(x);
  int lo = rot1_i32((int)(v & 0xffffffffLL));
  int hi = rot1_i32((int)(v >> 32));
  return __longlong_as_double(((long long)hi << 32) | (unsigned long long)(unsigned int)lo);
}

// ---------------------------------------------------------------------------
// K0 (f64) [validated R2]
// ---------------------------------------------------------------------------
__global__ __launch_bounds__(256) void prep_kernel(
    const float* __restrict__ mu_logvar, double* __restrict__ A, double* __restrict__ Kc) {
  int row = blockIdx.x * 4 + (threadIdx.x >> 6);   // b*256 + l
  int lane = threadIdx.x & 63;
  const float* src = mu_logvar + (size_t)row * (2 * NC);
  double mu = 0.0, lv = 0.0, iv = 0.0, part = 0.0;
  if (lane < NC) {
    mu = (double)src[lane];
    lv = (double)src[NC + lane];
    iv = exp(-lv);
    part = mu * mu * iv + lv;
  }
  for (int m = 1; m < 64; m <<= 1) part += __shfl_xor(part, m, 64);
  const double s = -0.5 / (double)NC;
  if (lane < NC) {
    A[(size_t)row * 80 + lane]      = s * iv;
    A[(size_t)row * 80 + NC + lane] = (1.0 / (double)NC) * mu * iv;
  }
  if (lane == 0) Kc[row] = s * part;
}

// ---------------------------------------------------------------------------
// K1 (f64) [validated math R2-R6]. Staging layout (2-wave DP split):
//   bufA2[(b*1600+t)*64 + i] = {d(2i),   d(2i+1)}    rows 0..127   (workspace)
//   bufB2[(b*1600+t)*64 + j] = {d(128+2j),d(129+2j)} rows 128..255 (align reg.)
// Alignment region is read-only during dp (zeroed by finalize afterwards) ->
// no cross-block races (R15 lesson).
// ---------------------------------------------------------------------------
__global__ __launch_bounds__(128) void lp_kernel(
    const float* __restrict__ z, const double* __restrict__ A,
    const double* __restrict__ Kc, float* out,
    float* __restrict__ lpTh) {
  int b  = blockIdx.z;
  int l0 = blockIdx.y * 32;
  int t0 = blockIdx.x * 128;
  int tid = threadIdx.x;
  int t = t0 + tid;
  int tv = imin(t, TLEN - 1);
  bool act = (t < TLEN);

  float* lp_out = out + OFF_LP;
  double2* bufA = (double2*)lpTh;
  double2* bufB = (double2*)(out + OFF_ALIGN);

  float zr[NC];
  const float* zb = z + (size_t)b * NC * TLEN;
  #pragma unroll
  for (int c = 0; c < NC; ++c) zr[c] = zb[(size_t)c * TLEN + tv];

  __shared__ __align__(16) double tile[128][17];
  const double* Ab = A + ((size_t)b * LLEN + l0) * 80;
  const double* Kb = Kc + (size_t)b * LLEN + l0;

  for (int g = 0; g < 2; ++g) {
    for (int j16 = 0; j16 < 16; ++j16) {
      int j = g * 16 + j16;
      const double* Ar = Ab + (size_t)j * 80;      // wave-uniform -> s_load
      double a0 = Kb[j], a1 = 0.0, a2 = 0.0, a3 = 0.0;
      #pragma unroll
      for (int c = 0; c < NC; c += 2) {
        double z0 = (double)zr[c], z1 = (double)zr[c + 1];
        a0 = fma(Ar[c],          z0 * z0, a0);
        a1 = fma(Ar[NC + c],     z0,      a1);
        a2 = fma(Ar[c + 1],      z1 * z1, a2);
        a3 = fma(Ar[NC + c + 1], z1,      a3);
      }
      double accd = (a0 + a2) + (a1 + a3);
      if (act) lp_out[((size_t)b * LLEN + l0 + j) * TLEN + t] = (float)accd;
      tile[tid][j16] = accd;
    }
    __syncthreads();
    {
      bool toB = (l0 + g * 16) >= 128;
      double2* dst = toB ? bufB : bufA;
      int slotbase = (l0 + g * 16) / 2 - (toB ? 64 : 0);
      #pragma unroll
      for (int p8 = 0; p8 < 8; ++p8) {
        int idx = p8 * 128 + tid;       // 0..1023
        int r = idx >> 3, s = idx & 7;
        int tr = t0 + r;
        if (tr < TLEN) {
          double2 d;
          d.x = tile[r][2 * s];
          d.y = tile[r][2 * s + 1];
          dst[((size_t)b * TLEN + tr) * 64 + slotbase + s] = d;
        }
      }
    }
    __syncthreads();
  }
}

// ---------------------------------------------------------------------------
// K2: DP. R18: 2-wave row split with DETERMINISTIC barrier pipeline (no spin,
// no flags -- R12/R13/R17 lesson). 52 iterations; iteration k: leader (wave 0,
// rows 0..127, 2/lane) runs chunk k (32 steps) then drains lgkm; follower
// (wave 1, rows 128..255) runs chunk k-2; unconditional s_barrier. Boundary
// values (LDS ring bndP/bndF, written per-step by leader lanes 0/63) that a
// follower step reads span chunks k-2/k-1 -> published >= 1 barrier earlier.
// Wrap bit (torch (r-1)%L for r=0: beta[255]@t > beta[0]@t) computed by the
// follower (owns row 255; leader streams beta[0]@t via bndP[t].y); follower
// is sole writer of Dbits[0] (leader suppresses lane0 a0 flush).
// MSB-first cmp+addc bit accumulate [R16-validated]; backtrack bit 31-(qq&31).
// No zeroing in dp (finalize restored) -> alignment staging is read-only.
// ---------------------------------------------------------------------------
__global__ __launch_bounds__(128, 1) void dp_kernel(
    const float* __restrict__ lpTh, const float* outR,
    const int* __restrict__ tlen, const int* __restrict__ mlen,
    float* out, int* __restrict__ pathg) {
  int bid = blockIdx.x;
  bool is_beta = (bid >= BB);
  int b = is_beta ? bid - BB : bid;
  int tid = threadIdx.x;
  int lane = tid & 63;
  int wv = tid >> 6;                    // 0 = leader (rows 0-127), 1 = follower
  int tl = tlen[b];
  int ml = mlen[b];
  const double2* pA = (const double2*)lpTh + (size_t)b * TLEN * 64;
  const double2* pB = (const double2*)(outR + OFF_ALIGN) + (size_t)b * TLEN * 64;

  __shared__ uint32_t Dbits[LLEN][TLEN / 32];   // 51.2 KB (beta)
  __shared__ int pathL[TLEN];                   // 6.4 KB
  __shared__ double2 bndP[1616];                // 25.9 KB boundary store
  float* bndF = (float*)bndP;

  const double2* myd = wv ? pB : pA;

  if (tid == 0) {
    if (is_beta) { bndP[0].x = NEGPADD; bndP[0].y = pA[0].x; }  // {b127@0, b0@0}
    else         { bndF[0] = NEGPADF; }
  }
  __syncthreads();

  // data ring prologue: cols 1..8
  double2 D0 = myd[1 * 64 + lane], D1 = myd[2 * 64 + lane];
  double2 D2 = myd[3 * 64 + lane], D3 = myd[4 * 64 + lane];
  double2 D4 = myd[5 * 64 + lane], D5 = myd[6 * 64 + lane];
  double2 D6 = myd[7 * 64 + lane], D7 = myd[8 * 64 + lane];

  if (!is_beta) {
    // ================= alpha: forward logsumexp (f32, log2) =================
    float lp00 = (float)pA[0].x * LOG2E_F;
    float o0 = (wv == 0 && lane == 0) ? lp00 : NEGPADF;
    float o1 = NEGPADF;
    float f0 = o0, f1 = o1;
    float qv = rot1_f32(o1);
    float bcar = 0.f, bq0 = 0.f, bq1 = 0.f, bq2 = 0.f, bq3 = 0.f;
    float bq4 = 0.f, bq5 = 0.f, bq6 = 0.f, bq7 = 0.f;
    int t = 1;
    auto stepL = [&](double2& D) {
      float v0 = (float)D.x, v1 = (float)D.y;
      int c = imin(t + 8, TLEN - 1);
      D = myd[(size_t)c * 64 + lane];
      float l0 = fmaf(v0, LOG2E_F, C7F);
      float l1 = fmaf(v1, LOG2E_F, C7F);
      float p = (lane == 0) ? NEGPADF : qv;
      float m0 = fmaxf(o0, p),  d0 = fabsf(o0 - p);
      float m1 = fmaxf(o1, o0), d1 = fabsf(o1 - o0);
      float y0 = __builtin_amdgcn_exp2f(-d0);
      float y1 = __builtin_amdgcn_exp2f(-d1);
      float s0 = y0 * fmaf(y0, fmaf(y0, PC_F, PB_F), PA_F);
      float s1 = y1 * fmaf(y1, fmaf(y1, PC_F, PB_F), PA_F);
      o0 = m0 + s0 + l0;
      o1 = m1 + s1 + l1;
      qv = rot1_f32(o1);
      if (lane == 63) bndF[t] = o1;            // alpha row 127 @ t
      if (t == ml - 1) { f0 = o0; f1 = o1; }
      ++t;
    };
    auto stepF = [&](double2& D, float& bq) {
      float v0 = (float)D.x, v1 = (float)D.y;
      int c = imin(t + 8, TLEN - 1);
      D = myd[(size_t)c * 64 + lane];
      float bc = bq;
      bq = bndF[t + 8];                        // idx <= 1608, in-bounds
      float l0 = fmaf(v0, LOG2E_F, C7F);
      float l1 = fmaf(v1, LOG2E_F, C7F);
      float p = (lane == 0) ? bcar : qv;       // alpha row 127 @ t-1
      float m0 = fmaxf(o0, p),  d0 = fabsf(o0 - p);
      float m1 = fmaxf(o1, o0), d1 = fabsf(o1 - o0);
      float y0 = __builtin_amdgcn_exp2f(-d0);
      float y1 = __builtin_amdgcn_exp2f(-d1);
      float s0 = y0 * fmaf(y0, fmaf(y0, PC_F, PB_F), PA_F);
      float s1 = y1 * fmaf(y1, fmaf(y1, PC_F, PB_F), PA_F);
      o0 = m0 + s0 + l0;
      o1 = m1 + s1 + l1;
      qv = rot1_f32(o1);
      bcar = bc;
      if (t == ml - 1) { f0 = o0; f1 = o1; }
      ++t;
    };
    for (int k = 0; k < NITER; ++k) {
      if (wv == 0) {
        if (k < NCHUNK) {
          #pragma unroll 1
          for (int u = 0; u < 4; ++u) {
            stepL(D0); stepL(D1); stepL(D2); stepL(D3);
            stepL(D4); stepL(D5); stepL(D6); stepL(D7);
          }
          __builtin_amdgcn_s_waitcnt(WAIT_LGKM0);   // bndF visible pre-barrier
        }
      } else {
        if (k == 1) {
          bcar = bndF[0];
          bq0 = bndF[1]; bq1 = bndF[2]; bq2 = bndF[3]; bq3 = bndF[4];
          bq4 = bndF[5]; bq5 = bndF[6]; bq6 = bndF[7]; bq7 = bndF[8];
        }
        if (k >= 2) {
          #pragma unroll 1
          for (int u = 0; u < 4; ++u) {
            stepF(D0, bq0); stepF(D1, bq1); stepF(D2, bq2); stepF(D3, bq3);
            stepF(D4, bq4); stepF(D5, bq5); stepF(D6, bq6); stepF(D7, bq7);
          }
        }
      }
      bar();
    }
    int fr = tl - 1;                    // row fr: wave fr>>7, lane (fr&127)>>1
    if ((fr >> 7) == wv && lane == ((fr & 127) >> 1)) {
      float val = (fr & 1) ? f1 : f0;
      out[b] = -val * LN2_F / (float)ml;
    }
    return;
  }

  // ==================== beta: Viterbi max-DP (f64) ==========================
  {
    double lp00 = pA[0].x;
    double o0 = (wv == 0 && lane == 0) ? lp00 : NEGPADD;
    double o1 = NEGPADD;
    uint32_t a0 = 0, a1 = (wv == 0 && lane == 0) ? 1u : 0u, aW = 0;
    double qv = rot1_f64(o1);
    double bcar = 0.0;
    double2 bq0, bq1, bq2, bq3, bq4, bq5, bq6, bq7;
    bq0 = bq1 = bq2 = bq3 = bq4 = bq5 = bq6 = bq7 = make_double2(0.0, 0.0);
    int t = 1;
    auto stepLb = [&](double2& D) {
      double l0 = D.x, l1 = D.y;
      int c = imin(t + 8, TLEN - 1);
      D = myd[(size_t)c * 64 + lane];
      double p = (lane == 0) ? NEGPADD : qv;
      double n0 = fmax(o0, p)  + l0;
      double n1 = fmax(o1, o0) + l1;
      qv = rot1_f64(n1);               // lane i: new beta row 2i-1
      asm("v_cmp_gt_f64 vcc, %1, %2\n\t"
          "v_addc_co_u32 %0, vcc, %0, %0, vcc"
          : "+v"(a0) : "v"(qv), "v"(n0) : "vcc");
      asm("v_cmp_gt_f64 vcc, %1, %2\n\t"
          "v_addc_co_u32 %0, vcc, %0, %0, vcc"
          : "+v"(a1) : "v"(n0), "v"(n1) : "vcc");
      o0 = n0; o1 = n1;
      if (lane == 63) bndP[t].x = n1;  // beta row 127 @ t
      if (lane == 0)  bndP[t].y = n0;  // beta row 0   @ t (wrap bit source)
      if ((t & 31) == 31) {
        int wd = t >> 5;
        if (lane != 0) Dbits[2 * lane][wd] = a0;   // row 0 owned by follower
        Dbits[2 * lane + 1][wd] = a1;
        a0 = 0; a1 = 0;
      }
      ++t;
    };
    auto stepFb = [&](double2& D, double2& bq) {
      double l0 = D.x, l1 = D.y;
      int c = imin(t + 8, TLEN - 1);
      D = myd[(size_t)c * 64 + lane];
      double2 bc = bq;
      bq = bndP[t + 8];                // idx <= 1608, in-bounds
      double p = (lane == 0) ? bcar : qv;      // beta row 127 @ t-1
      double n0 = fmax(o0, p)  + l0;
      double n1 = fmax(o1, o0) + l1;
      qv = rot1_f64(n1);
      double bx = (lane == 0) ? bc.x : qv;     // NEW beta[r-1]@t (127 for lane0)
      asm("v_cmp_gt_f64 vcc, %1, %2\n\t"
          "v_addc_co_u32 %0, vcc, %0, %0, vcc"
          : "+v"(a0) : "v"(bx), "v"(n0) : "vcc");
      asm("v_cmp_gt_f64 vcc, %1, %2\n\t"
          "v_addc_co_u32 %0, vcc, %0, %0, vcc"
          : "+v"(a1) : "v"(n0), "v"(n1) : "vcc");
      // wrap bit row 0: beta[255]@t > beta[0]@t (lane63: n1 vs bc.y)
      asm("v_cmp_gt_f64 vcc, %1, %2\n\t"
          "v_addc_co_u32 %0, vcc, %0, %0, vcc"
          : "+v"(aW) : "v"(n1), "v"(bc.y) : "vcc");
      o0 = n0; o1 = n1; bcar = bc.x;
      if ((t & 31) == 31) {
        int wd = t >> 5;
        Dbits[128 + 2 * lane][wd] = a0;
        Dbits[129 + 2 * lane][wd] = a1;
        if (lane == 63) Dbits[0][wd] = aW;
        a0 = 0; a1 = 0; aW = 0;
      }
      ++t;
    };
    for (int k = 0; k < NITER; ++k) {
      if (wv == 0) {
        if (k < NCHUNK) {
          #pragma unroll 1
          for (int u = 0; u < 4; ++u) {
            stepLb(D0); stepLb(D1); stepLb(D2); stepLb(D3);
            stepLb(D4); stepLb(D5); stepLb(D6); stepLb(D7);
          }
          __builtin_amdgcn_s_waitcnt(WAIT_LGKM0);   // bndP visible pre-barrier
        }
      } else {
        if (k == 1) {
          bcar = bndP[0].x;
          bq0 = bndP[1]; bq1 = bndP[2]; bq2 = bndP[3]; bq3 = bndP[4];
          bq4 = bndP[5]; bq5 = bndP[6]; bq6 = bndP[7]; bq7 = bndP[8];
        }
        if (k >= 2) {
          #pragma unroll 1
          for (int u = 0; u < 4; ++u) {
            stepFb(D0, bq0); stepFb(D1, bq1); stepFb(D2, bq2); stepFb(D3, bq3);
            stepFb(D4, bq4); stepFb(D5, bq5); stepFb(D6, bq6); stepFb(D7, bq7);
          }
        }
      }
      bar();
    }
  }
  __syncthreads();                      // all Dbits complete & visible

  // -------- literal backtrack [validated R2-R6], MSB-first bits -----------
  if (tid == 0) {
    int r = tl - 1;
    pathL[ml - 1] = r;
    int curR = 1 << 30, curW = -1;
    uint32_t W = 0;
    for (int qq = ml - 2; qq >= 0; --qq) {
      int w2 = qq >> 5;
      if (r >= 0 && (r != curR || w2 != curW)) { W = Dbits[r][w2]; curR = r; curW = w2; }
      int g = (r >= 0) ? (int)((W >> (31 - (qq & 31))) & 1u) : 0;
      r -= g;
      pathL[qq] = r;
    }
  }
  __syncthreads();
  for (int tt = tid; tt < ml; tt += 128) pathg[b * TLEN + tt] = pathL[tt];
}

// ---------------------------------------------------------------------------
// K3: zero alignment region + scatter one-hots [validated R0]
// ---------------------------------------------------------------------------
__global__ __launch_bounds__(256) void finalize_kernel(
    const int* __restrict__ mlen, const int* __restrict__ pathg,
    float* __restrict__ out) {
  int b = blockIdx.y;
  int t0 = blockIdx.x * 8;
  float* al = out + OFF_ALIGN + (size_t)b * TLEN * LLEN;
  float4 z4 = make_float4(0.f, 0.f, 0.f, 0.f);
  #pragma unroll
  for (int p = 0; p < 2; ++p) {
    int idx = p * 256 + threadIdx.x;
    int r = idx >> 6, c4 = idx & 63;
    *(float4*)(al + (size_t)(t0 + r) * LLEN + c4 * 4) = z4;
  }
  __syncthreads();
  if (threadIdx.x < 8) {
    int t = t0 + threadIdx.x;
    int ml = mlen[b];
    if (t < ml) {
      int p = pathg[b * TLEN + t];
      if (p >= 0) al[(size_t)t * LLEN + p] = 1.0f;
    }
  }
}

extern "C" void kernel_launch(void* const* d_in, const int* in_sizes, int n_in,
                              void* d_out, int out_size, void* d_ws, size_t ws_size,
                              hipStream_t stream) {
  const float* mu_logvar = (const float*)d_in[0];
  const float* z         = (const float*)d_in[1];
  const int*   tlv       = (const int*)d_in[2];
  const int*   mlv       = (const int*)d_in[3];
  float* out = (float*)d_out;
  char*  wsb = (char*)d_ws;

  double* Ad   = (double*)(wsb + WSB_A);
  double* Kcd  = (double*)(wsb + WSB_KC);
  float*  lpTh = (float*)(wsb + WSB_LPT);
  int*    path = (int*)(wsb + WSB_PATH);

  prep_kernel<<<dim3(BB * LLEN / 4), 256, 0, stream>>>(mu_logvar, Ad, Kcd);
  lp_kernel<<<dim3(13, 8, BB), 128, 0, stream>>>(z, Ad, Kcd, out, lpTh);
  dp_kernel<<<dim3(2 * BB), 128, 0, stream>>>(lpTh, out, tlv, mlv, out, path);
  finalize_kernel<<<dim3(TLEN / 8, BB), 256, 0, stream>>>(mlv, path, out);
}

// Round 12
// 480.932 us; speedup vs baseline: 1.2061x; 1.2061x over previous
//
#include <hip/hip_runtime.h>
#include <cstdint>
#include <math.h>

// Problem constants: B=32, TXT_T=256, MEL_T=1600, N_MEL=40
#define BB   32
#define LLEN 256
#define TLEN 1600
#define NC   40
#define NEGPADF (-1.0e12f)
#define NEGPADD (-1.0e12)
#define NBATCH 16           // DP columns per window
#define SUBB   8            // columns per producer sub-batch
#define NPROD  4            // producer waves
#define NBUF   3            // LDS column buffers (store-2-ahead)

#define LOG2E_F 1.4426950408889634f
#define LN2_F   0.6931471805599453f
#define C7F     1.4426950408889634e-7f  // 1e-7*log2e, folded into staged alpha lp
// log2(1+y) ~= y*(PA + y*(PB + y*PC)) on y in (0,1]; max err ~4e-3 [R16-validated]
#define PA_F 1.4426950f
#define PB_F (-0.6484000f)
#define PC_F 0.2057000f

// Output layout (floats): mdn_loss[32] | alignment[32*1600*256] | lp[32*256*1600]
#define OFF_ALIGN 32
#define OFF_LP    (32 + (size_t)BB * TLEN * LLEN)

// Workspace (bytes): Ad double[32*256*80] | Kcd double[32*256] | lpTh float[32*1600*256]
#define WSB_A    0
#define WSB_KC   (WSB_A + (size_t)BB * LLEN * 80 * 8)
#define WSB_LPT  (WSB_KC + (size_t)BB * LLEN * 8)

__device__ __forceinline__ int imin(int a, int b) { return a < b ? a : b; }

#define WAIT_LGKM0 0xC07F   // lgkmcnt(0) only, vmcnt untouched (validated R2-R6)

// Barrier draining LDS ops only: producer's future global loads stay in flight.
__device__ __forceinline__ void bar_prod() {
  asm volatile("" ::: "memory");
  __builtin_amdgcn_s_waitcnt(WAIT_LGKM0);
  __builtin_amdgcn_s_barrier();
  asm volatile("" ::: "memory");
}
__device__ __forceinline__ void bar_cons() {
  asm volatile("" ::: "memory");
  __builtin_amdgcn_s_barrier();
  asm volatile("" ::: "memory");
}

// DPP wave-rotate-right-1: lane i <- lane i-1, lane 0 <- lane 63. VALU-only.
__device__ __forceinline__ int rot1_i32(int x) {
  return __builtin_amdgcn_mov_dpp(x, 0x13C /*wave_ror:1*/, 0xF, 0xF, true);
}
__device__ __forceinline__ float rot1_f32(float x) {
  return __int_as_float(rot1_i32(__float_as_int(x)));
}
__device__ __forceinline__ double rot1_f64(double x) {
  long long v = __double_as_longlong(x);
  int lo = rot1_i32((int)(v & 0xffffffffLL));
  int hi = rot1_i32((int)(v >> 32));
  return __longlong_as_double(((long long)hi << 32) | (unsigned long long)(unsigned int)lo);
}

// ---------------------------------------------------------------------------
// K0 (f64) [validated R2]
// ---------------------------------------------------------------------------
__global__ __launch_bounds__(256) void prep_kernel(
    const float* __restrict__ mu_logvar, double* __restrict__ A, double* __restrict__ Kc) {
  int row = blockIdx.x * 4 + (threadIdx.x >> 6);   // b*256 + l
  int lane = threadIdx.x & 63;
  const float* src = mu_logvar + (size_t)row * (2 * NC);
  double mu = 0.0, lv = 0.0, iv = 0.0, part = 0.0;
  if (lane < NC) {
    mu = (double)src[lane];
    lv = (double)src[NC + lane];
    iv = exp(-lv);
    part = mu * mu * iv + lv;
  }
  for (int m = 1; m < 64; m <<= 1) part += __shfl_xor(part, m, 64);
  const double s = -0.5 / (double)NC;
  if (lane < NC) {
    A[(size_t)row * 80 + lane]      = s * iv;
    A[(size_t)row * 80 + NC + lane] = (1.0 / (double)NC) * mu * iv;
  }
  if (lane == 0) Kc[row] = s * part;
}

// ---------------------------------------------------------------------------
// K1 (f64) [validated R2/R3/R5/R6 math]: lp + hi/lo transposed copies.
// ---------------------------------------------------------------------------
__global__ __launch_bounds__(128) void lp_kernel(
    const float* __restrict__ z, const double* __restrict__ A,
    const double* __restrict__ Kc, float* __restrict__ out,
    float* __restrict__ lpTh) {
  int b  = blockIdx.z;
  int l0 = blockIdx.y * 32;
  int t0 = blockIdx.x * 128;
  int tid = threadIdx.x;
  int t = t0 + tid;
  int tv = imin(t, TLEN - 1);
  bool act = (t < TLEN);

  float* lp_out = out + OFF_LP;
  float* loS    = out + OFF_ALIGN;   // lo scratch [b][t][l], zeroed by dp tail

  float zr[NC];
  const float* zb = z + (size_t)b * NC * TLEN;
  #pragma unroll
  for (int c = 0; c < NC; ++c) zr[c] = zb[(size_t)c * TLEN + tv];

  __shared__ __align__(16) double tile[128][17];
  const double* Ab = A + ((size_t)b * LLEN + l0) * 80;
  const double* Kb = Kc + (size_t)b * LLEN + l0;

  for (int g = 0; g < 2; ++g) {
    for (int j16 = 0; j16 < 16; ++j16) {
      int j = g * 16 + j16;
      const double* Ar = Ab + (size_t)j * 80;      // wave-uniform -> s_load
      double a0 = Kb[j], a1 = 0.0, a2 = 0.0, a3 = 0.0;
      #pragma unroll
      for (int c = 0; c < NC; c += 2) {
        double z0 = (double)zr[c], z1 = (double)zr[c + 1];
        a0 = fma(Ar[c],          z0 * z0, a0);
        a1 = fma(Ar[NC + c],     z0,      a1);
        a2 = fma(Ar[c + 1],      z1 * z1, a2);
        a3 = fma(Ar[NC + c + 1], z1,      a3);
      }
      double accd = (a0 + a2) + (a1 + a3);
      if (act) lp_out[((size_t)b * LLEN + l0 + j) * TLEN + t] = (float)accd;
      tile[tid][j16] = accd;
    }
    __syncthreads();
    #pragma unroll
    for (int p = 0; p < 4; ++p) {
      int idx = p * 128 + tid;
      int r = idx >> 2, c4 = idx & 3;
      int tr = t0 + r;
      if (tr < TLEN) {
        float h[4], lo[4];
        #pragma unroll
        for (int i = 0; i < 4; ++i) {
          double d = tile[r][c4 * 4 + i];
          float hh = (float)d;
          h[i] = hh;
          lo[i] = (float)(d - (double)hh);
        }
        size_t base = ((size_t)b * TLEN + tr) * LLEN + l0 + g * 16 + c4 * 4;
        *(float4*)(lpTh + base) = make_float4(h[0], h[1], h[2], h[3]);
        *(float4*)(loS + base)  = make_float4(lo[0], lo[1], lo[2], lo[3]);
      }
    }
    __syncthreads();
  }
}

// ---------------------------------------------------------------------------
// K2: DP, 64 blocks x 320 threads (1 consumer + 4 producer waves).
// R19 = EXACT R9 structure (best measured: dp 221 us) + two R16-validated
// consumer-local instruction cuts:
//  - uniform nint = 100 for ALL blocks (dp time = slowest block at ml~1600
//    anyway; producers clamp col reads; alpha captures at t==ml-1; beta bits
//    past ml are never read). Every Dbits word gets exactly 32 shifts ->
//    MSB-first addc accumulate is exact; old partial-word tail guard deleted.
//  - beta bit-accumulate: v_cmp_f64 + v_addc (a=(a<<1)|bit, MSB-first),
//    2 VALU/row instead of 3. Backtrack reads bit 31-(qq&31); the a1=1 seed
//    (t=0 decision) lands on bit 31 of word 0 after 31 in-word shifts.
//  - alpha softplus poly: log2(1+2^-|d|) ~= y*(PA+y*(PB+y*PC)), y=exp2(-|d|).
//    4 trans/step instead of 8. Loss-error budget <=0.006 vs 0.45 threshold.
// Producer schedule, store-2-ahead NBUF=3, register-ring consumers, fused
// zero-fill + scatter: byte-for-byte R9 (validated R2-R9 audits).
// ---------------------------------------------------------------------------
__global__ __launch_bounds__(320, 1) void dp_kernel(
    const float* __restrict__ lpTh, const float* outR,
    const int* __restrict__ tlen, const int* __restrict__ mlen,
    float* __restrict__ out) {
  int bid = blockIdx.x;
  bool is_beta = (bid >= BB);
  int b = is_beta ? bid - BB : bid;
  int tid = threadIdx.x;
  int lane = tid & 63;
  int wv = tid >> 6;                   // 0 = consumer, 1..4 = producers
  int tl = tlen[b];
  int ml = mlen[b];
  const float* lpb = lpTh + (size_t)b * TLEN * LLEN;
  const float* lob = outR + OFF_ALIGN + (size_t)b * TLEN * LLEN;
  float* al = out + OFF_ALIGN + (size_t)b * TLEN * LLEN;
  const int nint = TLEN / NBATCH;      // uniform 100 windows (R19)
  const int nsb  = 2 * nint;           // 200 sub-batches

  __shared__ __align__(16) double bufd[NBUF][NBATCH][4][64];   // beta cols, 96 KB
  __shared__ uint32_t Dbits[LLEN][TLEN / 32];                  // 51.2 KB
  __shared__ int pathL[TLEN];                                  // 6.4 KB
  float* bufaF = (float*)&bufd[0][0][0][0];   // alpha aliases bufd

  if (wv >= 1) {
    // ---------------- producers [R9-validated schedule] --------------------
    int q = wv - 1;
    const float* ph = lpb + 4 * lane;
    const float* pl = lob + 4 * lane;
    float4 vh[SUBB], vl[SUBB];
    float4 z4 = make_float4(0.f, 0.f, 0.f, 0.f);
    auto issue = [&](int sb) {
      #pragma unroll
      for (int j = 0; j < SUBB; ++j) {
        int c = imin(1 + SUBB * sb + j, TLEN - 1);
        vh[j] = *(const float4*)(ph + (size_t)c * LLEN);
        if (is_beta) vl[j] = *(const float4*)(pl + (size_t)c * LLEN);
      }
    };
    auto store = [&](int sb) {
      int s  = (sb >> 1) % NBUF;
      int jb = (sb & 1) * SUBB;
      if (is_beta) {
        #pragma unroll
        for (int j = 0; j < SUBB; ++j) {
          bufd[s][jb + j][0][lane] = (double)vh[j].x + (double)vl[j].x;
          bufd[s][jb + j][1][lane] = (double)vh[j].y + (double)vl[j].y;
          bufd[s][jb + j][2][lane] = (double)vh[j].z + (double)vl[j].z;
          bufd[s][jb + j][3][lane] = (double)vh[j].w + (double)vl[j].w;
        }
      } else {
        #pragma unroll
        for (int j = 0; j < SUBB; ++j) {
          int off = ((s * NBATCH + jb + j) * 4) * 64 + lane;
          bufaF[off]       = fmaf(vh[j].x, LOG2E_F, C7F);
          bufaF[off + 64]  = fmaf(vh[j].y, LOG2E_F, C7F);
          bufaF[off + 128] = fmaf(vh[j].z, LOG2E_F, C7F);
          bufaF[off + 192] = fmaf(vh[j].w, LOG2E_F, C7F);
        }
      }
    };
    // prologue: windows 0 AND 1 (sb 0..3) staged before barrier -1;
    // sb 4..7 (windows 2,3) loads in flight.
    if (q < nsb) {
      issue(q); store(q);
      if (q + NPROD < nsb) issue(q + NPROD);
    }
    bar_prod();                        // barrier -1 (consumer prefetches win 0)
    for (int w = 0; w < nint; ++w) {
      bar_prod();
      int sb0 = 2 * w + 4;             // store window w+2
      int mine = ((sb0 & 3) == q) ? sb0 : ((((sb0 + 1) & 3) == q) ? (sb0 + 1) : -1);
      if (mine >= 0 && mine < nsb) {
        store(mine);                   // vmcnt wait: only own batch outstanding
        if (mine + NPROD < nsb) issue(mine + NPROD);
      }
      // fused-finalize zero-fill: cols [16(w-1),16w) consumed; outstanding
      // loads target cols >= 16w+33 under the store-2-ahead schedule.
      if (is_beta && w >= 1) {
        int zc = NBATCH * (w - 1) + 4 * q;
        float* az = al + (size_t)zc * LLEN + 4 * lane;
        #pragma unroll
        for (int k = 0; k < 4; ++k) *(float4*)(az + (size_t)k * LLEN) = z4;
      }
    }
    // tail zero: cols [16(nint-1), 1600)
    if (is_beta) {
      for (int c = NBATCH * (nint - 1) + q; c < TLEN; c += NPROD)
        *(float4*)(al + (size_t)c * LLEN + 4 * lane) = z4;
    }
  } else if (!is_beta) {
    // ---------------- consumer: forward logsumexp (f32, log2 domain) -------
    float lp00 = lpb[0] * LOG2E_F;
    float o0 = (lane == 0) ? lp00 : NEGPADF;
    float o1 = NEGPADF, o2 = NEGPADF, o3 = NEGPADF;
    float f0 = o0, f1 = o1, f2 = o2, f3 = o3;
    float qv = rot1_f32(o3);
    bar_cons();                        // barrier -1: windows 0,1 staged
    float P[4][4];
    #pragma unroll
    for (int i = 0; i < 4; ++i) {      // prefetch window 0 steps 0..3
      const float* src = bufaF + i * 256;
      P[i][0] = src[lane]; P[i][1] = src[64 + lane];
      P[i][2] = src[128 + lane]; P[i][3] = src[192 + lane];
    }
    int t = 1;
    for (int w = 0; w < nint; ++w) {
      bar_cons();
      int s = w % NBUF, sn = (w + 1) % NBUF;
      const float* baseS = bufaF + s * (NBATCH * 256);
      const float* baseN = bufaF + sn * (NBATCH * 256);
      #pragma unroll
      for (int j = 0; j < NBATCH; ++j, ++t) {
        int rj = j & 3;
        float l0 = P[rj][0], l1 = P[rj][1], l2 = P[rj][2], l3 = P[rj][3];
        const float* src = (j < NBATCH - 4) ? (baseS + (j + 4) * 256)
                                            : (baseN + (j + 4 - NBATCH) * 256);
        P[rj][0] = src[lane];       P[rj][1] = src[64 + lane];
        P[rj][2] = src[128 + lane]; P[rj][3] = src[192 + lane];
        float p = (lane == 0) ? NEGPADF : qv;
        float m0 = fmaxf(o0, p),  d0 = fabsf(o0 - p);
        float m1 = fmaxf(o1, o0), d1 = fabsf(o1 - o0);
        float m2 = fmaxf(o2, o1), d2 = fabsf(o2 - o1);
        float m3 = fmaxf(o3, o2), d3 = fabsf(o3 - o2);
        // softplus poly [R16-validated]: log2(1+2^-d) ~= y*(PA+y*(PB+y*PC))
        float y0 = __builtin_amdgcn_exp2f(-d0);
        float y1 = __builtin_amdgcn_exp2f(-d1);
        float y2 = __builtin_amdgcn_exp2f(-d2);
        float y3 = __builtin_amdgcn_exp2f(-d3);
        float n0 = m0 + y0 * fmaf(y0, fmaf(y0, PC_F, PB_F), PA_F) + l0;
        float n1 = m1 + y1 * fmaf(y1, fmaf(y1, PC_F, PB_F), PA_F) + l1;
        float n2 = m2 + y2 * fmaf(y2, fmaf(y2, PC_F, PB_F), PA_F) + l2;
        float n3 = m3 + y3 * fmaf(y3, fmaf(y3, PC_F, PB_F), PA_F) + l3;
        o0 = n0; o1 = n1; o2 = n2; o3 = n3;
        qv = rot1_f32(o3);
        if (t == ml - 1) { f0 = o0; f1 = o1; f2 = o2; f3 = o3; }
      }
    }
    int fr = tl - 1;
    if (lane == (fr >> 2)) {
      int sx = fr & 3;
      float val = (sx == 0) ? f0 : (sx == 1) ? f1 : (sx == 2) ? f2 : f3;
      out[b] = -val * LN2_F / (float)ml;
    }
  } else {
    // ---------------- consumer: Viterbi max-DP (f64) -----------------------
    double lp00 = (double)lpb[0] + (double)lob[0];
    double o0 = (lane == 0) ? lp00 : NEGPADD;
    double o1 = NEGPADD, o2 = NEGPADD, o3 = NEGPADD;
    // shift-accumulate decision words (MSB-first); a1 seed = t=0 decision.
    uint32_t a0 = 0, a1 = (lane == 0) ? 1u : 0u, a2 = 0, a3 = 0;
    double qv = rot1_f64(o3);
    bar_cons();                        // barrier -1: windows 0,1 staged
    double P[4][4];
    #pragma unroll
    for (int i = 0; i < 4; ++i) {      // prefetch window 0 steps 0..3
      P[i][0] = bufd[0][i][0][lane]; P[i][1] = bufd[0][i][1][lane];
      P[i][2] = bufd[0][i][2][lane]; P[i][3] = bufd[0][i][3][lane];
    }
    int t = 1;
    for (int w = 0; w < nint; ++w) {
      bar_cons();
      int s = w % NBUF, sn = (w + 1) % NBUF;
      const double (*bs)[4][64] = bufd[s];
      const double (*bn)[4][64] = bufd[sn];
      #pragma unroll
      for (int j = 0; j < NBATCH; ++j, ++t) {
        int rj = j & 3;
        double l0 = P[rj][0], l1 = P[rj][1], l2 = P[rj][2], l3 = P[rj][3];
        {
          const double (*src)[64] = (j < NBATCH - 4) ? bs[j + 4] : bn[j + 4 - NBATCH];
          P[rj][0] = src[0][lane]; P[rj][1] = src[1][lane];
          P[rj][2] = src[2][lane]; P[rj][3] = src[3][lane];
        }
        double p = (lane == 0) ? NEGPADD : qv;
        double n0 = fmax(o0, p)  + l0;
        double n1 = fmax(o1, o0) + l1;
        double n2 = fmax(o2, o1) + l2;
        double n3 = fmax(o3, o2) + l3;
        qv = rot1_f64(n3);                // row 4i-1 (mod 256) new beta
        // a = (a<<1) | (x>y)  via cmp -> vcc -> addc (2 insts/row) [R16]
        asm("v_cmp_gt_f64 vcc, %1, %2\n\t"
            "v_addc_co_u32 %0, vcc, %0, %0, vcc"
            : "+v"(a0) : "v"(qv), "v"(n0) : "vcc");
        asm("v_cmp_gt_f64 vcc, %1, %2\n\t"
            "v_addc_co_u32 %0, vcc, %0, %0, vcc"
            : "+v"(a1) : "v"(n0), "v"(n1) : "vcc");
        asm("v_cmp_gt_f64 vcc, %1, %2\n\t"
            "v_addc_co_u32 %0, vcc, %0, %0, vcc"
            : "+v"(a2) : "v"(n1), "v"(n2) : "vcc");
        asm("v_cmp_gt_f64 vcc, %1, %2\n\t"
            "v_addc_co_u32 %0, vcc, %0, %0, vcc"
            : "+v"(a3) : "v"(n2), "v"(n3) : "vcc");
        o0 = n0; o1 = n1; o2 = n2; o3 = n3;
        if ((t & 31) == 31) {
          int wd = t >> 5;
          Dbits[4 * lane + 0][wd] = a0; a0 = 0;
          Dbits[4 * lane + 1][wd] = a1; a1 = 0;
          Dbits[4 * lane + 2][wd] = a2; a2 = 0;
          Dbits[4 * lane + 3][wd] = a3; a3 = 0;
        }
      }
    }
    // uniform 1600-step loop: words 0..49 all complete (last flush t=1599);
    // t=1600's bits are dropped (qq only reaches ml-2 <= 1598). No tail guard.
    __builtin_amdgcn_s_waitcnt(WAIT_LGKM0);  // drain own-wave LDS ops

    // -------- literal backtrack [validated R2-R6], MSB-first bits ----------
    if (lane == 0) {
      int r = tl - 1;
      pathL[ml - 1] = r;
      int curR = 1 << 30, curW = -1;
      uint32_t W = 0;
      for (int qq = ml - 2; qq >= 0; --qq) {
        int w2 = qq >> 5;
        if (r >= 0 && (r != curR || w2 != curW)) { W = Dbits[r][w2]; curR = r; curW = w2; }
        int g = (r >= 0) ? (int)((W >> (31 - (qq & 31))) & 1u) : 0;
        r -= g;
        pathL[qq] = r;
      }
    }
  }

  // -------- fused finalize tail: scatter one-hots (beta blocks only) -------
  if (is_beta) {
    __syncthreads();                    // zero-fill + pathL complete
    for (int t = tid; t < ml; t += 320) {
      int p = pathL[t];
      if (p >= 0) al[(size_t)t * LLEN + p] = 1.0f;
    }
  }
}

extern "C" void kernel_launch(void* const* d_in, const int* in_sizes, int n_in,
                              void* d_out, int out_size, void* d_ws, size_t ws_size,
                              hipStream_t stream) {
  const float* mu_logvar = (const float*)d_in[0];
  const float* z         = (const float*)d_in[1];
  const int*   tlv       = (const int*)d_in[2];
  const int*   mlv       = (const int*)d_in[3];
  float* out = (float*)d_out;
  char*  wsb = (char*)d_ws;

  double* Ad   = (double*)(wsb + WSB_A);
  double* Kcd  = (double*)(wsb + WSB_KC);
  float*  lpTh = (float*)(wsb + WSB_LPT);

  prep_kernel<<<dim3(BB * LLEN / 4), 256, 0, stream>>>(mu_logvar, Ad, Kcd);
  lp_kernel<<<dim3(13, 8, BB), 128, 0, stream>>>(z, Ad, Kcd, out, lpTh);
  dp_kernel<<<dim3(2 * BB), 320, 0, stream>>>(lpTh, out, tlv, mlv, out);
}